// Round 4
// baseline (305.255 us; speedup 1.0000x reference)
//
#include <hip/hip_runtime.h>

// Problem constants
#define T_LEN 4096
#define DMODEL 512
#define DIM 512
#define NBATCH 8
#define MROWS (NBATCH * T_LEN)   // 32768
#define NCHUNK 128
#define LCHUNK 32                 // T_LEN / NCHUNK

typedef __attribute__((ext_vector_type(8))) short short8;
typedef __attribute__((ext_vector_type(4))) float float4v;

__device__ __forceinline__ ushort f2b(float f) {
    union { float fl; unsigned u; } v; v.fl = f;
    unsigned u = v.u;
    return (ushort)((u + 0x7FFFu + ((u >> 16) & 1u)) >> 16);
}
__device__ __forceinline__ float b2f(ushort u) {
    union { unsigned u; float f; } v; v.u = (unsigned)u << 16; return v.f;
}

__device__ __forceinline__ void glds16(const ushort* g, ushort* l) {
    __builtin_amdgcn_global_load_lds(
        (const __attribute__((address_space(1))) void*)g,
        (__attribute__((address_space(3))) void*)l, 16, 0, 0);
}

// ---------------- merged prep kernel (R1 structure, known-good) ----------------
#define XBLK (MROWS * 512 / 4 / 256)        // 16384
#define BBLK (1024 * 512 / 256)             // 2048
#define CBLK (512 * 1024 / 256)             // 2048

__global__ __launch_bounds__(256) void k_prep(const float* __restrict__ x,
                                              const float* __restrict__ B_re,
                                              const float* __restrict__ B_im,
                                              const float* __restrict__ gamma_log,
                                              const float* __restrict__ C_re,
                                              const float* __restrict__ C_im,
                                              ushort* __restrict__ Xb,
                                              ushort* __restrict__ BT,
                                              ushort* __restrict__ CT) {
    int bb = blockIdx.x;
    if (bb < XBLK) {
        int i = (bb * 256 + threadIdx.x) * 4;
        float4 v = *(const float4*)(x + i);
        ushort4 o;
        o.x = f2b(v.x); o.y = f2b(v.y); o.z = f2b(v.z); o.w = f2b(v.w);
        *(ushort4*)(Xb + i) = o;
    } else if (bb < XBLK + BBLK) {
        int idx = (bb - XBLK) * 256 + threadIdx.x;   // 0 .. 1024*512-1
        int n = idx >> 9;
        int d = idx & 511;
        float v;
        if (n < 512) v = B_re[d * 512 + n] * __expf(gamma_log[n]);
        else { int nn = n - 512; v = B_im[d * 512 + nn] * __expf(gamma_log[nn]); }
        BT[idx] = f2b(v);
    } else {
        int idx = (bb - XBLK - BBLK) * 256 + threadIdx.x;  // 0 .. 512*1024-1
        int d = idx >> 10;
        int k = idx & 1023;
        float v = (k < 512) ? C_re[k * 512 + d] : -C_im[(k - 512) * 512 + d];
        CT[idx] = f2b(v);
    }
}

// ---------------- GEMM: BM=256, BN=128, BK=64; 512 thr = 8 waves (4m x 2n) ----------------
// 3-deep LDS pipeline (144 KB): stage tile t+2 issued BEFORE compute(t); counted
// s_waitcnt vmcnt(6) (= loads of one tile) before a RAW s_barrier — tile t+2's loads
// stay in flight across the barrier (no compiler vmcnt(0) drain; this is the whole point
// vs __syncthreads). Buffers rotate mod 3 via pointer swap (no dynamic indexing).
// LDS row = 8 chunks of 8 ushort, chunk XOR-swizzled by (row&7): 0 bank conflicts
// (verified in counters on the 128^2 ancestor; identical lane math).

__device__ __forceinline__ void stage_tileA(const ushort* gA0, long koff, ushort* sAb,
                                            int wave) {
#pragma unroll
    for (int c = 0; c < 4; c++)   // wave w stages A rows [w*32, w*32+32)
        glds16(gA0 + (long)(c * 8) * 0 + koff + 0, nullptr); // placeholder (unused)
}

template<int K>
__device__ __forceinline__ void stage_tile(const ushort* gA0, const ushort* gB0, int kt,
                                           ushort* sAb, ushort* sBb, int wave) {
    const long ko = (long)kt * 64;
#pragma unroll
    for (int c = 0; c < 4; c++)   // A: wave w rows [w*32, +32), 8 rows/instr
        glds16(gA0 + (long)(c * 8) * K + ko, &sAb[(wave * 32 + c * 8) * 64]);
#pragma unroll
    for (int c = 0; c < 2; c++)   // B: wave w rows [w*16, +16), 8 rows/instr
        glds16(gB0 + (long)(c * 8) * K + ko, &sBb[(wave * 16 + c * 8) * 64]);
}

__device__ __forceinline__ void compute_tile(const ushort* sAb, const ushort* sBb,
                                             int wm, int wn, int lr, int quad,
                                             float4v acc[4][4]) {
#pragma unroll
    for (int kk = 0; kk < 2; kk++) {
        short8 af[4], bfr[4];
#pragma unroll
        for (int i = 0; i < 4; i++) {
            int row = wm + i * 16 + lr;
            af[i] = *(const short8*)&sAb[row * 64 + (((kk * 4 + quad) ^ (row & 7)) * 8)];
        }
#pragma unroll
        for (int j = 0; j < 4; j++) {
            int row = wn + j * 16 + lr;
            bfr[j] = *(const short8*)&sBb[row * 64 + (((kk * 4 + quad) ^ (row & 7)) * 8)];
        }
        __builtin_amdgcn_s_setprio(1);
#pragma unroll
        for (int i = 0; i < 4; i++)
#pragma unroll
            for (int j = 0; j < 4; j++)
                acc[i][j] = __builtin_amdgcn_mfma_f32_16x16x32_bf16(af[i], bfr[j], acc[i][j], 0, 0, 0);
        __builtin_amdgcn_s_setprio(0);
    }
}

template<int K, int MODE, int NBN>
__global__ __launch_bounds__(512) void k_gemm(
    const ushort* __restrict__ A, const ushort* __restrict__ Bt,
    ushort* __restrict__ oRe, ushort* __restrict__ oIm,
    float* __restrict__ y, const float* __restrict__ x, const float* __restrict__ Dp) {
    const int NT = K / 64;                  // 8 (GEMM1) or 16 (GEMM2)
    __shared__ ushort sA[3][256 * 64];      // 96 KB
    __shared__ ushort sB[3][128 * 64];      // 48 KB
    const int tid = threadIdx.x;
    // XCD-aware remap: round-robin block->XCD (L%8); XCD owns a 16-m-block band.
    const int L = blockIdx.x;
    const int xcd = L & 7;
    const int slot = L >> 3;
    const int m0 = (xcd * 16 + slot / NBN) * 256;
    const int n0 = (slot % NBN) * 128;
    const int wave = tid >> 6;              // 0..7
    const int lane = tid & 63;
    const int wm = (wave >> 1) * 64;        // 0,64,128,192
    const int wn = (wave & 1) * 64;         // 0,64
    const int lr = lane & 15;
    const int quad = lane >> 4;

    const int srow = lane >> 3;             // 0..7 within 8-row group
    const int schunk = (lane & 7) ^ srow;   // XOR swizzle key = row&7 = srow
    const ushort* gA0 = A + (size_t)(m0 + wave * 32 + srow) * K + schunk * 8;
    const ushort* gB0 = Bt + (size_t)(n0 + wave * 16 + srow) * K + schunk * 8;

    float4v acc[4][4];
#pragma unroll
    for (int i = 0; i < 4; i++)
#pragma unroll
        for (int j = 0; j < 4; j++) {
            float4v z = {0.f, 0.f, 0.f, 0.f};
            acc[i][j] = z;
        }

    // rotating buffer pointers: a0 = compute, a1 = landing (t+1), a2 = stage dest (t+2)
    ushort *a0 = &sA[0][0], *a1 = &sA[1][0], *a2 = &sA[2][0];
    ushort *b0 = &sB[0][0], *b1 = &sB[1][0], *b2 = &sB[2][0];

    // prologue: tiles 0,1 in flight (12 outstanding); vmcnt(6) = tile 0 landed
    stage_tile<K>(gA0, gB0, 0, a0, b0, wave);
    stage_tile<K>(gA0, gB0, 1, a1, b1, wave);
    asm volatile("s_waitcnt vmcnt(6)" ::: "memory");
    __builtin_amdgcn_s_barrier();
    __builtin_amdgcn_sched_barrier(0);

    for (int t = 0; t < NT; ++t) {
        if (t + 2 < NT)
            stage_tile<K>(gA0, gB0, t + 2, a2, b2, wave);   // into free buffer, issued early
        compute_tile(a0, b0, wm, wn, lr, quad, acc);
        if (t + 2 < NT) {
            asm volatile("s_waitcnt vmcnt(6)" ::: "memory"); // tile t+1 landed; t+2 in flight
        } else {
            asm volatile("s_waitcnt vmcnt(0)" ::: "memory"); // tail: drain last tile
        }
        __builtin_amdgcn_s_barrier();
        __builtin_amdgcn_sched_barrier(0);
        ushort* ta = a0; a0 = a1; a1 = a2; a2 = ta;
        ushort* tb = b0; b0 = b1; b1 = b2; b2 = tb;
    }

    // epilogue: D[row][col], col = lane&15, row = quad*4 + r
#pragma unroll
    for (int i = 0; i < 4; i++) {
#pragma unroll
        for (int j = 0; j < 4; j++) {
            int gmb = m0 + wm + i * 16 + quad * 4;
            int gn = n0 + wn + j * 16 + lr;
#pragma unroll
            for (int r = 0; r < 4; r++) {
                float v = acc[i][j][r];
                int row = gmb + r;
                if (MODE == 1) {
                    if (gn < 512) oRe[(size_t)row * 512 + gn] = f2b(v);
                    else oIm[(size_t)row * 512 + (gn - 512)] = f2b(v);
                } else {
                    size_t o = (size_t)row * 512 + gn;
                    y[o] = v + Dp[gn] * x[o];
                }
            }
        }
    }
}

// ---------------- scan kernels (unchanged, verified) ----------------

__device__ __forceinline__ void lambda_of(const float* nu_log, const float* theta_log,
                                          int n, float& lre, float& lim) {
    float e = __expf(nu_log[n]);
    float th = __expf(theta_log[n]);
    float rad = __expf(-e);
    float s, c;
    __sincosf(th, &s, &c);
    lre = rad * c;
    lim = rad * s;
}

__global__ __launch_bounds__(256) void k_scan1(const ushort* __restrict__ BuRe,
                                               const ushort* __restrict__ BuIm,
                                               const float* __restrict__ nu_log,
                                               const float* __restrict__ theta_log,
                                               float* __restrict__ cRe, float* __restrict__ cIm) {
    int n2 = threadIdx.x;
    int b = blockIdx.x >> 7;
    int c = blockIdx.x & 127;
    float lre0, lim0, lre1, lim1;
    lambda_of(nu_log, theta_log, 2 * n2, lre0, lim0);
    lambda_of(nu_log, theta_log, 2 * n2 + 1, lre1, lim1);
    float hr0 = 0.f, hi0 = 0.f, hr1 = 0.f, hi1 = 0.f;
    size_t base = ((size_t)b * T_LEN + (size_t)c * LCHUNK) * 512 + 2 * n2;
#pragma unroll 8
    for (int j = 0; j < LCHUNK; j++) {
        ushort2 ur = *(const ushort2*)(BuRe + base + (size_t)j * 512);
        ushort2 ui = *(const ushort2*)(BuIm + base + (size_t)j * 512);
        float br0 = b2f(ur.x), br1 = b2f(ur.y), bi0 = b2f(ui.x), bi1 = b2f(ui.y);
        float nr0 = lre0 * hr0 - lim0 * hi0 + br0;
        float ni0 = lre0 * hi0 + lim0 * hr0 + bi0;
        hr0 = nr0; hi0 = ni0;
        float nr1 = lre1 * hr1 - lim1 * hi1 + br1;
        float ni1 = lre1 * hi1 + lim1 * hr1 + bi1;
        hr1 = nr1; hi1 = ni1;
    }
    size_t co = ((size_t)b * NCHUNK + c) * 512 + 2 * n2;
    *(float2*)(cRe + co) = make_float2(hr0, hr1);
    *(float2*)(cIm + co) = make_float2(hi0, hi1);
}

__global__ __launch_bounds__(64) void k_scan2(const float* __restrict__ cRe,
                                              const float* __restrict__ cIm,
                                              const float* __restrict__ h0,
                                              const float* __restrict__ nu_log,
                                              const float* __restrict__ theta_log,
                                              float* __restrict__ pRe, float* __restrict__ pIm,
                                              float* __restrict__ newH, int newh_mode) {
    int idx = blockIdx.x * 64 + threadIdx.x;   // 0..4095
    int b = idx >> 9;
    int n = idx & 511;
    float lre, lim;
    lambda_of(nu_log, theta_log, n, lre, lim);
    float Lr = lre, Li = lim;
#pragma unroll
    for (int s = 0; s < 5; s++) {
        float nr = Lr * Lr - Li * Li;
        float ni = 2.f * Lr * Li;
        Lr = nr; Li = ni;
    }
    float cr = h0[b * 512 + n];
    float ci = 0.f;
#pragma unroll 4
    for (int c = 0; c < NCHUNK; c++) {
        size_t o = ((size_t)b * NCHUNK + c) * 512 + n;
        pRe[o] = cr;
        pIm[o] = ci;
        float ar = cRe[o], ai = cIm[o];
        float nr = Lr * cr - Li * ci + ar;
        float ni = Lr * ci + Li * cr + ai;
        cr = nr; ci = ni;
    }
    size_t ci_idx = (size_t)b * 512 + n;
    if (newh_mode == 1) {
        newH[ci_idx] = cr;
        newH[(size_t)NBATCH * 512 + ci_idx] = ci;
    } else if (newh_mode == 2) {
        newH[ci_idx] = cr;
    } else {
        newH[ci_idx * 2] = cr;
        newH[ci_idx * 2 + 1] = ci;
    }
}

__global__ __launch_bounds__(256) void k_scan3(const ushort* __restrict__ BuRe,
                                               const ushort* __restrict__ BuIm,
                                               const float* __restrict__ pRe,
                                               const float* __restrict__ pIm,
                                               const float* __restrict__ nu_log,
                                               const float* __restrict__ theta_log,
                                               ushort* __restrict__ Hbf) {
    int n2 = threadIdx.x;
    int b = blockIdx.x >> 7;
    int c = blockIdx.x & 127;
    float lre0, lim0, lre1, lim1;
    lambda_of(nu_log, theta_log, 2 * n2, lre0, lim0);
    lambda_of(nu_log, theta_log, 2 * n2 + 1, lre1, lim1);
    size_t co = ((size_t)b * NCHUNK + c) * 512 + 2 * n2;
    float2 frv = *(const float2*)(pRe + co);
    float2 fiv = *(const float2*)(pIm + co);
    float fr0 = frv.x, fr1 = frv.y, fi0 = fiv.x, fi1 = fiv.y;
    float pr0 = lre0, pi0 = lim0, pr1 = lre1, pi1 = lim1;
    float hr0 = 0.f, hi0 = 0.f, hr1 = 0.f, hi1 = 0.f;
    size_t row0 = (size_t)b * T_LEN + (size_t)c * LCHUNK;
#pragma unroll 4
    for (int j = 0; j < LCHUNK; j++) {
        size_t base = (row0 + j) * 512 + 2 * n2;
        ushort2 ur = *(const ushort2*)(BuRe + base);
        ushort2 ui = *(const ushort2*)(BuIm + base);
        float br0 = b2f(ur.x), br1 = b2f(ur.y), bi0 = b2f(ui.x), bi1 = b2f(ui.y);
        float nr0 = lre0 * hr0 - lim0 * hi0 + br0;
        float ni0 = lre0 * hi0 + lim0 * hr0 + bi0;
        hr0 = nr0; hi0 = ni0;
        float nr1 = lre1 * hr1 - lim1 * hi1 + br1;
        float ni1 = lre1 * hi1 + lim1 * hr1 + bi1;
        hr1 = nr1; hi1 = ni1;
        float vr0 = hr0 + pr0 * fr0 - pi0 * fi0;
        float vi0 = hi0 + pr0 * fi0 + pi0 * fr0;
        float vr1 = hr1 + pr1 * fr1 - pi1 * fi1;
        float vi1 = hi1 + pr1 * fi1 + pi1 * fr1;
        size_t hrow = (row0 + j) * 1024;
        ushort2 wre, wim;
        wre.x = f2b(vr0); wre.y = f2b(vr1);
        wim.x = f2b(vi0); wim.y = f2b(vi1);
        *(ushort2*)(Hbf + hrow + 2 * n2) = wre;
        *(ushort2*)(Hbf + hrow + 512 + 2 * n2) = wim;
        float npr0 = pr0 * lre0 - pi0 * lim0;
        float npi0 = pr0 * lim0 + pi0 * lre0;
        pr0 = npr0; pi0 = npi0;
        float npr1 = pr1 * lre1 - pi1 * lim1;
        float npi1 = pr1 * lim1 + pi1 * lre1;
        pr1 = npr1; pi1 = npi1;
    }
}

// ---------------- launch ----------------

extern "C" void kernel_launch(void* const* d_in, const int* in_sizes, int n_in,
                              void* d_out, int out_size, void* d_ws, size_t ws_size,
                              hipStream_t stream) {
    const float* x         = (const float*)d_in[0];
    const float* h0        = (const float*)d_in[1];
    const float* nu_log    = (const float*)d_in[2];
    const float* theta_log = (const float*)d_in[3];
    const float* B_re      = (const float*)d_in[4];
    const float* B_im      = (const float*)d_in[5];
    const float* C_re      = (const float*)d_in[6];
    const float* C_im      = (const float*)d_in[7];
    const float* D_param   = (const float*)d_in[8];
    const float* gamma_log = (const float*)d_in[9];

    char* ws = (char*)d_ws;
    size_t off = 0;
    ushort* Xb   = (ushort*)(ws + off); off += (size_t)MROWS * 512 * 2;
    ushort* BT   = (ushort*)(ws + off); off += (size_t)1024 * 512 * 2;
    ushort* CT   = (ushort*)(ws + off); off += (size_t)512 * 1024 * 2;
    ushort* BuRe = (ushort*)(ws + off); off += (size_t)MROWS * 512 * 2;
    ushort* BuIm = (ushort*)(ws + off); off += (size_t)MROWS * 512 * 2;
    ushort* Hbf  = (ushort*)(ws + off); off += (size_t)MROWS * 1024 * 2;
    float*  cRe  = (float*)(ws + off); off += (size_t)NBATCH * NCHUNK * 512 * 4;
    float*  cIm  = (float*)(ws + off); off += (size_t)NBATCH * NCHUNK * 512 * 4;
    float*  pRe  = (float*)(ws + off); off += (size_t)NBATCH * NCHUNK * 512 * 4;
    float*  pIm  = (float*)(ws + off); off += (size_t)NBATCH * NCHUNK * 512 * 4;

    float* y_out = (float*)d_out;
    float* newH  = (float*)d_out + (size_t)MROWS * 512;

    const int tail = out_size - MROWS * 512;
    int newh_mode = 0;
    if (tail == NBATCH * 512 * 2) newh_mode = 1;       // planar [re|im] (validated R2)
    else if (tail == NBATCH * 512) newh_mode = 2;

    // merged prep: x->bf16, BT, CT in one launch
    k_prep<<<dim3(XBLK + BBLK + CBLK), dim3(256), 0, stream>>>(
        x, B_re, B_im, gamma_log, C_re, C_im, Xb, BT, CT);

    // GEMM1: Bu(bf16 planes) = Xb (32768x512) * BT^T (512x1024); 256x128 tiles -> 1024 blocks
    k_gemm<512, 1, 8><<<dim3(1024), dim3(512), 0, stream>>>(
        Xb, BT, BuRe, BuIm, nullptr, nullptr, nullptr);

    // scan
    k_scan1<<<dim3(NBATCH * NCHUNK), dim3(256), 0, stream>>>(BuRe, BuIm, nu_log, theta_log, cRe, cIm);
    k_scan2<<<dim3(NBATCH * 512 / 64), dim3(64), 0, stream>>>(cRe, cIm, h0, nu_log, theta_log, pRe, pIm, newH, newh_mode);
    k_scan3<<<dim3(NBATCH * NCHUNK), dim3(256), 0, stream>>>(BuRe, BuIm, pRe, pIm, nu_log, theta_log, Hbf);

    // GEMM2: y = Hbf (32768x1024) * CT^T (1024x512) + D*x; 256x128 tiles -> 512 blocks
    k_gemm<1024, 2, 4><<<dim3(512), dim3(512), 0, stream>>>(
        Hbf, CT, nullptr, nullptr, y_out, x, D_param);
}

// Round 5
// 296.920 us; speedup vs baseline: 1.0281x; 1.0281x over previous
//
#include <hip/hip_runtime.h>

// Problem constants
#define T_LEN 4096
#define DMODEL 512
#define DIM 512
#define NBATCH 8
#define MROWS (NBATCH * T_LEN)   // 32768
#define NCHUNK 128
#define LCHUNK 32                 // T_LEN / NCHUNK

typedef __attribute__((ext_vector_type(8))) short short8;
typedef __attribute__((ext_vector_type(4))) float float4v;

__device__ __forceinline__ ushort f2b(float f) {
    union { float fl; unsigned u; } v; v.fl = f;
    unsigned u = v.u;
    return (ushort)((u + 0x7FFFu + ((u >> 16) & 1u)) >> 16);
}
__device__ __forceinline__ float b2f(ushort u) {
    union { unsigned u; float f; } v; v.u = (unsigned)u << 16; return v.f;
}

__device__ __forceinline__ void glds16(const ushort* g, ushort* l) {
    __builtin_amdgcn_global_load_lds(
        (const __attribute__((address_space(1))) void*)g,
        (__attribute__((address_space(3))) void*)l, 16, 0, 0);
}

// ---------------- merged prep kernel (R1 structure, known-good) ----------------
#define XBLK (MROWS * 512 / 4 / 256)        // 16384
#define BBLK (1024 * 512 / 256)             // 2048
#define CBLK (512 * 1024 / 256)             // 2048

__global__ __launch_bounds__(256) void k_prep(const float* __restrict__ x,
                                              const float* __restrict__ B_re,
                                              const float* __restrict__ B_im,
                                              const float* __restrict__ gamma_log,
                                              const float* __restrict__ C_re,
                                              const float* __restrict__ C_im,
                                              ushort* __restrict__ Xb,
                                              ushort* __restrict__ BT,
                                              ushort* __restrict__ CT) {
    int bb = blockIdx.x;
    if (bb < XBLK) {
        int i = (bb * 256 + threadIdx.x) * 4;
        float4 v = *(const float4*)(x + i);
        ushort4 o;
        o.x = f2b(v.x); o.y = f2b(v.y); o.z = f2b(v.z); o.w = f2b(v.w);
        *(ushort4*)(Xb + i) = o;
    } else if (bb < XBLK + BBLK) {
        int idx = (bb - XBLK) * 256 + threadIdx.x;   // 0 .. 1024*512-1
        int n = idx >> 9;
        int d = idx & 511;
        float v;
        if (n < 512) v = B_re[d * 512 + n] * __expf(gamma_log[n]);
        else { int nn = n - 512; v = B_im[d * 512 + nn] * __expf(gamma_log[nn]); }
        BT[idx] = f2b(v);
    } else {
        int idx = (bb - XBLK - BBLK) * 256 + threadIdx.x;  // 0 .. 512*1024-1
        int d = idx >> 10;
        int k = idx & 1023;
        float v = (k < 512) ? C_re[k * 512 + d] : -C_im[(k - 512) * 512 + d];
        CT[idx] = f2b(v);
    }
}

// ---------------- bf16 MFMA GEMM (R1-exact; best measured: 65 us GEMM1) ----------------
// BM=BN=128, BK=64, 256 thr = 4 waves 2x2, wave = 64x64 via 4x4 MFMA 16x16x32 (x2 k-steps).
// glds16 staging; LDS row = 8 chunks of 8 ushort, chunk XOR-swizzled by (row&7): 0 bank
// conflicts (counter-verified). 2-barrier loop; ~4 blocks/CU give inter-block overlap
// (m114). Pipelining attempts R2/R3/R4 all regressed — do not re-add without the FULL
// 8-phase interleave.
template<int K, int MODE, int NBN>
__global__ __launch_bounds__(256) void k_gemm(
    const ushort* __restrict__ A, const ushort* __restrict__ Bt,
    ushort* __restrict__ oRe, ushort* __restrict__ oIm,
    float* __restrict__ y, const float* __restrict__ x, const float* __restrict__ Dp) {
    __shared__ ushort sA[128 * 64];
    __shared__ ushort sB[128 * 64];
    const int tid = threadIdx.x;
    // swizzle: assume round-robin block->XCD (L%8). XCD owns 256/8=32 m-blocks, all n.
    const int L = blockIdx.x;
    const int xcd = L & 7;
    const int slot = L >> 3;
    const int m0 = (xcd * 32 + slot / NBN) * 128;
    const int n0 = (slot % NBN) * 128;
    const int wave = tid >> 6;
    const int lane = tid & 63;
    const int wm = (wave >> 1) * 64;
    const int wn = (wave & 1) * 64;
    const int lr = lane & 15;
    const int quad = lane >> 4;

    // staging: wave w covers rows [w*32, w*32+32), 4 calls x 8 rows per matrix.
    const int srow = lane >> 3;                 // 0..7 within 8-row group
    const int schunk = (lane & 7) ^ srow;       // XOR swizzle key = row&7 = srow
    const ushort* gA0 = A + (size_t)(m0 + wave * 32 + srow) * K + schunk * 8;
    const ushort* gB0 = Bt + (size_t)(n0 + wave * 32 + srow) * K + schunk * 8;

    float4v acc[4][4];
#pragma unroll
    for (int i = 0; i < 4; i++)
#pragma unroll
        for (int j = 0; j < 4; j++) {
            float4v z = {0.f, 0.f, 0.f, 0.f};
            acc[i][j] = z;
        }

    for (int k0 = 0; k0 < K; k0 += 64) {
        __syncthreads();
#pragma unroll
        for (int c = 0; c < 4; c++) {
            glds16(gA0 + (size_t)(c * 8) * K + k0, &sA[(wave * 32 + c * 8) * 64]);
            glds16(gB0 + (size_t)(c * 8) * K + k0, &sB[(wave * 32 + c * 8) * 64]);
        }
        __syncthreads();

#pragma unroll
        for (int kk = 0; kk < 2; kk++) {
            short8 af[4], bfr[4];
#pragma unroll
            for (int i = 0; i < 4; i++) {
                int row = wm + i * 16 + lr;
                af[i] = *(const short8*)&sA[row * 64 + (((kk * 4 + quad) ^ (row & 7)) * 8)];
            }
#pragma unroll
            for (int j = 0; j < 4; j++) {
                int row = wn + j * 16 + lr;
                bfr[j] = *(const short8*)&sB[row * 64 + (((kk * 4 + quad) ^ (row & 7)) * 8)];
            }
#pragma unroll
            for (int i = 0; i < 4; i++)
#pragma unroll
                for (int j = 0; j < 4; j++)
                    acc[i][j] = __builtin_amdgcn_mfma_f32_16x16x32_bf16(af[i], bfr[j], acc[i][j], 0, 0, 0);
        }
    }

    // epilogue: D[row][col], col = lane&15, row = quad*4 + r
#pragma unroll
    for (int i = 0; i < 4; i++) {
#pragma unroll
        for (int j = 0; j < 4; j++) {
            int gmb = m0 + wm + i * 16 + quad * 4;
            int gn = n0 + wn + j * 16 + lr;
#pragma unroll
            for (int r = 0; r < 4; r++) {
                float v = acc[i][j][r];
                int row = gmb + r;
                if (MODE == 1) {
                    if (gn < 512) oRe[(size_t)row * 512 + gn] = f2b(v);
                    else oIm[(size_t)row * 512 + (gn - 512)] = f2b(v);
                } else {
                    size_t o = (size_t)row * 512 + gn;
                    y[o] = v + Dp[gn] * x[o];
                }
            }
        }
    }
}

// ---------------- scan kernels ----------------

__device__ __forceinline__ void lambda_of(const float* nu_log, const float* theta_log,
                                          int n, float& lre, float& lim) {
    float e = __expf(nu_log[n]);
    float th = __expf(theta_log[n]);
    float rad = __expf(-e);
    float s, c;
    __sincosf(th, &s, &c);
    lre = rad * c;
    lim = rad * s;
}

// phase 1: per (b, chunk) local scan from zero.
// R5: vectorized — 4 channels/thread, ushort4 (8B) loads, float4 carry stores.
// Block covers 2 chunks: tid>>7 = chunk half, tid&127 = channel group. Grid = 8*64.
__global__ __launch_bounds__(256) void k_scan1(const ushort* __restrict__ BuRe,
                                               const ushort* __restrict__ BuIm,
                                               const float* __restrict__ nu_log,
                                               const float* __restrict__ theta_log,
                                               float* __restrict__ cRe, float* __restrict__ cIm) {
    int cg = threadIdx.x & 127;            // channels 4cg..4cg+3
    int b = blockIdx.x >> 6;
    int c = ((blockIdx.x & 63) << 1) + (threadIdx.x >> 7);
    float lre[4], lim[4], hr[4], hi[4];
#pragma unroll
    for (int q = 0; q < 4; q++) {
        lambda_of(nu_log, theta_log, 4 * cg + q, lre[q], lim[q]);
        hr[q] = 0.f; hi[q] = 0.f;
    }
    size_t base = ((size_t)b * T_LEN + (size_t)c * LCHUNK) * 512 + 4 * cg;
#pragma unroll 8
    for (int j = 0; j < LCHUNK; j++) {
        ushort4 ur = *(const ushort4*)(BuRe + base + (size_t)j * 512);
        ushort4 ui = *(const ushort4*)(BuIm + base + (size_t)j * 512);
        float br[4] = {b2f(ur.x), b2f(ur.y), b2f(ur.z), b2f(ur.w)};
        float bi[4] = {b2f(ui.x), b2f(ui.y), b2f(ui.z), b2f(ui.w)};
#pragma unroll
        for (int q = 0; q < 4; q++) {
            float nr = lre[q] * hr[q] - lim[q] * hi[q] + br[q];
            float ni = lre[q] * hi[q] + lim[q] * hr[q] + bi[q];
            hr[q] = nr; hi[q] = ni;
        }
    }
    size_t co = ((size_t)b * NCHUNK + c) * 512 + 4 * cg;
    *(float4*)(cRe + co) = make_float4(hr[0], hr[1], hr[2], hr[3]);
    *(float4*)(cIm + co) = make_float4(hi[0], hi[1], hi[2], hi[3]);
}

// phase 2: combine carries across chunks (unchanged; latency-tolerant via unroll-4 prefetch)
__global__ __launch_bounds__(64) void k_scan2(const float* __restrict__ cRe,
                                              const float* __restrict__ cIm,
                                              const float* __restrict__ h0,
                                              const float* __restrict__ nu_log,
                                              const float* __restrict__ theta_log,
                                              float* __restrict__ pRe, float* __restrict__ pIm,
                                              float* __restrict__ newH, int newh_mode) {
    int idx = blockIdx.x * 64 + threadIdx.x;   // 0..4095
    int b = idx >> 9;
    int n = idx & 511;
    float lre, lim;
    lambda_of(nu_log, theta_log, n, lre, lim);
    // lambda^LCHUNK via 5 squarings (LCHUNK = 32)
    float Lr = lre, Li = lim;
#pragma unroll
    for (int s = 0; s < 5; s++) {
        float nr = Lr * Lr - Li * Li;
        float ni = 2.f * Lr * Li;
        Lr = nr; Li = ni;
    }
    float cr = h0[b * 512 + n];
    float ci = 0.f;
#pragma unroll 4
    for (int c = 0; c < NCHUNK; c++) {
        size_t o = ((size_t)b * NCHUNK + c) * 512 + n;
        pRe[o] = cr;
        pIm[o] = ci;
        float ar = cRe[o], ai = cIm[o];
        float nr = Lr * cr - Li * ci + ar;
        float ni = Lr * ci + Li * cr + ai;
        cr = nr; ci = ni;
    }
    size_t ci_idx = (size_t)b * 512 + n;
    if (newh_mode == 1) {
        newH[ci_idx] = cr;
        newH[(size_t)NBATCH * 512 + ci_idx] = ci;
    } else if (newh_mode == 2) {
        newH[ci_idx] = cr;
    } else {
        newH[ci_idx * 2] = cr;
        newH[ci_idx * 2 + 1] = ci;
    }
}

// phase 3: recompute local scan + lambda^{j+1}*entering, write H bf16 [re|im] rows.
// R5: vectorized — 4 channels/thread, ushort4 loads AND stores. Grid = 8*64, 2 chunks/block.
__global__ __launch_bounds__(256) void k_scan3(const ushort* __restrict__ BuRe,
                                               const ushort* __restrict__ BuIm,
                                               const float* __restrict__ pRe,
                                               const float* __restrict__ pIm,
                                               const float* __restrict__ nu_log,
                                               const float* __restrict__ theta_log,
                                               ushort* __restrict__ Hbf) {
    int cg = threadIdx.x & 127;            // channels 4cg..4cg+3
    int b = blockIdx.x >> 6;
    int c = ((blockIdx.x & 63) << 1) + (threadIdx.x >> 7);
    float lre[4], lim[4], pr[4], pi[4], hr[4], hi[4];
#pragma unroll
    for (int q = 0; q < 4; q++) {
        lambda_of(nu_log, theta_log, 4 * cg + q, lre[q], lim[q]);
        pr[q] = lre[q]; pi[q] = lim[q];
        hr[q] = 0.f; hi[q] = 0.f;
    }
    size_t co = ((size_t)b * NCHUNK + c) * 512 + 4 * cg;
    float4 frv = *(const float4*)(pRe + co);
    float4 fiv = *(const float4*)(pIm + co);
    float fr[4] = {frv.x, frv.y, frv.z, frv.w};
    float fi[4] = {fiv.x, fiv.y, fiv.z, fiv.w};
    size_t row0 = (size_t)b * T_LEN + (size_t)c * LCHUNK;
#pragma unroll 4
    for (int j = 0; j < LCHUNK; j++) {
        size_t base = (row0 + j) * 512 + 4 * cg;
        ushort4 ur = *(const ushort4*)(BuRe + base);
        ushort4 ui = *(const ushort4*)(BuIm + base);
        float br[4] = {b2f(ur.x), b2f(ur.y), b2f(ur.z), b2f(ur.w)};
        float bi[4] = {b2f(ui.x), b2f(ui.y), b2f(ui.z), b2f(ui.w)};
        ushort4 wre, wim;
#pragma unroll
        for (int q = 0; q < 4; q++) {
            float nr = lre[q] * hr[q] - lim[q] * hi[q] + br[q];
            float ni = lre[q] * hi[q] + lim[q] * hr[q] + bi[q];
            hr[q] = nr; hi[q] = ni;
            float vr = hr[q] + pr[q] * fr[q] - pi[q] * fi[q];
            float vi = hi[q] + pr[q] * fi[q] + pi[q] * fr[q];
            ushort wr = f2b(vr), wi = f2b(vi);
            if (q == 0) { wre.x = wr; wim.x = wi; }
            else if (q == 1) { wre.y = wr; wim.y = wi; }
            else if (q == 2) { wre.z = wr; wim.z = wi; }
            else { wre.w = wr; wim.w = wi; }
            float npr = pr[q] * lre[q] - pi[q] * lim[q];
            float npi = pr[q] * lim[q] + pi[q] * lre[q];
            pr[q] = npr; pi[q] = npi;
        }
        size_t hrow = (row0 + j) * 1024;
        *(ushort4*)(Hbf + hrow + 4 * cg) = wre;
        *(ushort4*)(Hbf + hrow + 512 + 4 * cg) = wim;
    }
}

// ---------------- launch ----------------

extern "C" void kernel_launch(void* const* d_in, const int* in_sizes, int n_in,
                              void* d_out, int out_size, void* d_ws, size_t ws_size,
                              hipStream_t stream) {
    const float* x         = (const float*)d_in[0];
    const float* h0        = (const float*)d_in[1];
    const float* nu_log    = (const float*)d_in[2];
    const float* theta_log = (const float*)d_in[3];
    const float* B_re      = (const float*)d_in[4];
    const float* B_im      = (const float*)d_in[5];
    const float* C_re      = (const float*)d_in[6];
    const float* C_im      = (const float*)d_in[7];
    const float* D_param   = (const float*)d_in[8];
    const float* gamma_log = (const float*)d_in[9];

    char* ws = (char*)d_ws;
    size_t off = 0;
    ushort* Xb   = (ushort*)(ws + off); off += (size_t)MROWS * 512 * 2;
    ushort* BT   = (ushort*)(ws + off); off += (size_t)1024 * 512 * 2;
    ushort* CT   = (ushort*)(ws + off); off += (size_t)512 * 1024 * 2;
    ushort* BuRe = (ushort*)(ws + off); off += (size_t)MROWS * 512 * 2;
    ushort* BuIm = (ushort*)(ws + off); off += (size_t)MROWS * 512 * 2;
    ushort* Hbf  = (ushort*)(ws + off); off += (size_t)MROWS * 1024 * 2;
    float*  cRe  = (float*)(ws + off); off += (size_t)NBATCH * NCHUNK * 512 * 4;
    float*  cIm  = (float*)(ws + off); off += (size_t)NBATCH * NCHUNK * 512 * 4;
    float*  pRe  = (float*)(ws + off); off += (size_t)NBATCH * NCHUNK * 512 * 4;
    float*  pIm  = (float*)(ws + off); off += (size_t)NBATCH * NCHUNK * 512 * 4;

    float* y_out = (float*)d_out;
    float* newH  = (float*)d_out + (size_t)MROWS * 512;

    const int tail = out_size - MROWS * 512;
    int newh_mode = 0;
    if (tail == NBATCH * 512 * 2) newh_mode = 1;       // planar [re|im] (validated R2)
    else if (tail == NBATCH * 512) newh_mode = 2;

    // merged prep: x->bf16, BT, CT in one launch
    k_prep<<<dim3(XBLK + BBLK + CBLK), dim3(256), 0, stream>>>(
        x, B_re, B_im, gamma_log, C_re, C_im, Xb, BT, CT);

    // GEMM1: Bu(bf16 planes) = Xb (32768x512) * BT^T (512x1024); 2048 blocks
    k_gemm<512, 1, 8><<<dim3(2048), dim3(256), 0, stream>>>(
        Xb, BT, BuRe, BuIm, nullptr, nullptr, nullptr);

    // scan (scan1/scan3: 2 chunks per block, 4 channels per thread)
    k_scan1<<<dim3(NBATCH * NCHUNK / 2), dim3(256), 0, stream>>>(BuRe, BuIm, nu_log, theta_log, cRe, cIm);
    k_scan2<<<dim3(NBATCH * 512 / 64), dim3(64), 0, stream>>>(cRe, cIm, h0, nu_log, theta_log, pRe, pIm, newH, newh_mode);
    k_scan3<<<dim3(NBATCH * NCHUNK / 2), dim3(256), 0, stream>>>(BuRe, BuIm, pRe, pIm, nu_log, theta_log, Hbf);

    // GEMM2: y = Hbf (32768x1024) * CT^T (1024x512) + D*x; 1024 blocks
    k_gemm<1024, 2, 4><<<dim3(1024), dim3(256), 0, stream>>>(
        Hbf, CT, nullptr, nullptr, y_out, x, D_param);
}

// Round 6
// 285.670 us; speedup vs baseline: 1.0686x; 1.0394x over previous
//
#include <hip/hip_runtime.h>

// Problem constants
#define T_LEN 4096
#define DMODEL 512
#define DIM 512
#define NBATCH 8
#define MROWS (NBATCH * T_LEN)   // 32768
#define NCHUNK 128
#define LCHUNK 32                 // T_LEN / NCHUNK

typedef __attribute__((ext_vector_type(8))) short short8;
typedef __attribute__((ext_vector_type(4))) float float4v;

__device__ __forceinline__ ushort f2b(float f) {
    union { float fl; unsigned u; } v; v.fl = f;
    unsigned u = v.u;
    return (ushort)((u + 0x7FFFu + ((u >> 16) & 1u)) >> 16);
}
__device__ __forceinline__ float b2f(ushort u) {
    union { unsigned u; float f; } v; v.u = (unsigned)u << 16; return v.f;
}

__device__ __forceinline__ void glds16(const ushort* g, ushort* l) {
    __builtin_amdgcn_global_load_lds(
        (const __attribute__((address_space(1))) void*)g,
        (__attribute__((address_space(3))) void*)l, 16, 0, 0);
}

// ---------------- merged prep kernel ----------------
// blocks [0, XBLK): x f32 -> bf16 (unchanged, coalesced)
// blocks [XBLK, XBLK+256): 4 matrices (B_re,B_im,C_re,C_im) transposed via LDS
//   64x64 tiles — coalesced reads AND writes (old version read stride-2KB, ~16x overfetch).
#define XBLK (MROWS * 512 / 4 / 256)        // 16384
#define TBLK 256                            // 4 mats x 64 tiles of 64x64

__global__ __launch_bounds__(256) void k_prep(const float* __restrict__ x,
                                              const float* __restrict__ B_re,
                                              const float* __restrict__ B_im,
                                              const float* __restrict__ gamma_log,
                                              const float* __restrict__ C_re,
                                              const float* __restrict__ C_im,
                                              ushort* __restrict__ Xb,
                                              ushort* __restrict__ BT,
                                              ushort* __restrict__ CT) {
    __shared__ float T[64][65];
    int bb = blockIdx.x;
    if (bb < XBLK) {
        int i = (bb * 256 + threadIdx.x) * 4;
        float4 v = *(const float4*)(x + i);
        ushort4 o;
        o.x = f2b(v.x); o.y = f2b(v.y); o.z = f2b(v.z); o.w = f2b(v.w);
        *(ushort4*)(Xb + i) = o;
        return;
    }
    int tb = bb - XBLK;                 // 0..255
    int mat = tb >> 6;                  // 0=B_re 1=B_im 2=C_re 3=C_im
    int tile = tb & 63;
    int r0 = (tile >> 3) * 64;          // output row block
    int c0 = (tile & 7) * 64;           // output col block
    const float* IN = (mat == 0) ? B_re : (mat == 1) ? B_im : (mat == 2) ? C_re : C_im;
    int lr_ = threadIdx.x & 63;
    int lc  = threadIdx.x >> 6;
    // load IN[c][r] coalesced (lanes walk r = IN's fast dim)
#pragma unroll
    for (int p = 0; p < 16; p++)
        T[4 * p + lc][lr_] = IN[(size_t)(c0 + 4 * p + lc) * 512 + r0 + lr_];
    __syncthreads();
    // store OUT[r][c] coalesced (lanes walk c); scale applied per-row
#pragma unroll
    for (int p = 0; p < 16; p++) {
        int rr = 4 * p + lc;
        int r = r0 + rr;
        float v = T[lr_][rr];           // stride-65 read: conflict-free
        if (mat <= 1) {
            v *= __expf(gamma_log[r]);  // BT[n][d] = B[d][n]*exp(gamma[n])
            BT[(size_t)(mat * 512 + r) * 512 + c0 + lr_] = f2b(v);
        } else {
            if (mat == 3) v = -v;       // CT[d][512+k] = -C_im[k][d]
            CT[(size_t)r * 1024 + (mat - 2) * 512 + c0 + lr_] = f2b(v);
        }
    }
}

// ---------------- bf16 MFMA GEMM (R1-exact; best measured) ----------------
// BM=BN=128, BK=64, 256 thr = 4 waves 2x2, wave = 64x64 via 4x4 MFMA 16x16x32 (x2 k-steps).
// glds16 staging; LDS chunk XOR-swizzle by (row&7): 0 bank conflicts (counter-verified).
// 2-barrier loop; ~4 blocks/CU inter-block overlap. Pipelining attempts R2/R3/R4 all
// regressed — do not re-add without the FULL 8-phase interleave.
template<int K, int MODE, int NBN>
__global__ __launch_bounds__(256) void k_gemm(
    const ushort* __restrict__ A, const ushort* __restrict__ Bt,
    ushort* __restrict__ oRe, ushort* __restrict__ oIm,
    float* __restrict__ y, const float* __restrict__ x, const float* __restrict__ Dp) {
    __shared__ ushort sA[128 * 64];
    __shared__ ushort sB[128 * 64];
    const int tid = threadIdx.x;
    const int L = blockIdx.x;
    const int xcd = L & 7;
    const int slot = L >> 3;
    const int m0 = (xcd * 32 + slot / NBN) * 128;
    const int n0 = (slot % NBN) * 128;
    const int wave = tid >> 6;
    const int lane = tid & 63;
    const int wm = (wave >> 1) * 64;
    const int wn = (wave & 1) * 64;
    const int lr = lane & 15;
    const int quad = lane >> 4;

    const int srow = lane >> 3;                 // 0..7 within 8-row group
    const int schunk = (lane & 7) ^ srow;       // XOR swizzle key = row&7 = srow
    const ushort* gA0 = A + (size_t)(m0 + wave * 32 + srow) * K + schunk * 8;
    const ushort* gB0 = Bt + (size_t)(n0 + wave * 32 + srow) * K + schunk * 8;

    float4v acc[4][4];
#pragma unroll
    for (int i = 0; i < 4; i++)
#pragma unroll
        for (int j = 0; j < 4; j++) {
            float4v z = {0.f, 0.f, 0.f, 0.f};
            acc[i][j] = z;
        }

    for (int k0 = 0; k0 < K; k0 += 64) {
        __syncthreads();
#pragma unroll
        for (int c = 0; c < 4; c++) {
            glds16(gA0 + (size_t)(c * 8) * K + k0, &sA[(wave * 32 + c * 8) * 64]);
            glds16(gB0 + (size_t)(c * 8) * K + k0, &sB[(wave * 32 + c * 8) * 64]);
        }
        __syncthreads();

#pragma unroll
        for (int kk = 0; kk < 2; kk++) {
            short8 af[4], bfr[4];
#pragma unroll
            for (int i = 0; i < 4; i++) {
                int row = wm + i * 16 + lr;
                af[i] = *(const short8*)&sA[row * 64 + (((kk * 4 + quad) ^ (row & 7)) * 8)];
            }
#pragma unroll
            for (int j = 0; j < 4; j++) {
                int row = wn + j * 16 + lr;
                bfr[j] = *(const short8*)&sB[row * 64 + (((kk * 4 + quad) ^ (row & 7)) * 8)];
            }
#pragma unroll
            for (int i = 0; i < 4; i++)
#pragma unroll
                for (int j = 0; j < 4; j++)
                    acc[i][j] = __builtin_amdgcn_mfma_f32_16x16x32_bf16(af[i], bfr[j], acc[i][j], 0, 0, 0);
        }
    }

#pragma unroll
    for (int i = 0; i < 4; i++) {
#pragma unroll
        for (int j = 0; j < 4; j++) {
            int gmb = m0 + wm + i * 16 + quad * 4;
            int gn = n0 + wn + j * 16 + lr;
#pragma unroll
            for (int r = 0; r < 4; r++) {
                float v = acc[i][j][r];
                int row = gmb + r;
                if (MODE == 1) {
                    if (gn < 512) oRe[(size_t)row * 512 + gn] = f2b(v);
                    else oIm[(size_t)row * 512 + (gn - 512)] = f2b(v);
                } else {
                    size_t o = (size_t)row * 512 + gn;
                    y[o] = v + Dp[gn] * x[o];
                }
            }
        }
    }
}

// ---------------- scan kernels ----------------

__device__ __forceinline__ void lambda_of(const float* nu_log, const float* theta_log,
                                          int n, float& lre, float& lim) {
    float e = __expf(nu_log[n]);
    float th = __expf(theta_log[n]);
    float rad = __expf(-e);
    float s, c;
    __sincosf(th, &s, &c);
    lre = rad * c;
    lim = rad * s;
}

// phase 1: per (b, chunk) local scan from zero; 256 threads x 2 channels (R1-verified)
__global__ __launch_bounds__(256) void k_scan1(const ushort* __restrict__ BuRe,
                                               const ushort* __restrict__ BuIm,
                                               const float* __restrict__ nu_log,
                                               const float* __restrict__ theta_log,
                                               float* __restrict__ cRe, float* __restrict__ cIm) {
    int n2 = threadIdx.x;
    int b = blockIdx.x >> 7;
    int c = blockIdx.x & 127;
    float lre0, lim0, lre1, lim1;
    lambda_of(nu_log, theta_log, 2 * n2, lre0, lim0);
    lambda_of(nu_log, theta_log, 2 * n2 + 1, lre1, lim1);
    float hr0 = 0.f, hi0 = 0.f, hr1 = 0.f, hi1 = 0.f;
    size_t base = ((size_t)b * T_LEN + (size_t)c * LCHUNK) * 512 + 2 * n2;
#pragma unroll 8
    for (int j = 0; j < LCHUNK; j++) {
        ushort2 ur = *(const ushort2*)(BuRe + base + (size_t)j * 512);
        ushort2 ui = *(const ushort2*)(BuIm + base + (size_t)j * 512);
        float br0 = b2f(ur.x), br1 = b2f(ur.y), bi0 = b2f(ui.x), bi1 = b2f(ui.y);
        float nr0 = lre0 * hr0 - lim0 * hi0 + br0;
        float ni0 = lre0 * hi0 + lim0 * hr0 + bi0;
        hr0 = nr0; hi0 = ni0;
        float nr1 = lre1 * hr1 - lim1 * hi1 + br1;
        float ni1 = lre1 * hi1 + lim1 * hr1 + bi1;
        hr1 = nr1; hi1 = ni1;
    }
    size_t co = ((size_t)b * NCHUNK + c) * 512 + 2 * n2;
    *(float2*)(cRe + co) = make_float2(hr0, hr1);
    *(float2*)(cIm + co) = make_float2(hi0, hi1);
}

// scanB: replaces scan2 + scan3. Each block (b,c) recomputes its own entering prefix
// via Horner over carries 0..c-1 (identical op sequence as old scan2 -> bit-identical p),
// then runs the phase-3 body with p in registers. Block (b,127) emits newH.
// No pRe/pIm buffers, no latency-bound scan2 dispatch.
__global__ __launch_bounds__(256) void k_scanB(const ushort* __restrict__ BuRe,
                                               const ushort* __restrict__ BuIm,
                                               const float* __restrict__ cRe,
                                               const float* __restrict__ cIm,
                                               const float* __restrict__ h0,
                                               const float* __restrict__ nu_log,
                                               const float* __restrict__ theta_log,
                                               ushort* __restrict__ Hbf,
                                               float* __restrict__ newH, int newh_mode) {
    int n2 = threadIdx.x;
    int b = blockIdx.x >> 7;
    int c = blockIdx.x & 127;
    float lre0, lim0, lre1, lim1;
    lambda_of(nu_log, theta_log, 2 * n2, lre0, lim0);
    lambda_of(nu_log, theta_log, 2 * n2 + 1, lre1, lim1);
    // Lambda^LCHUNK via 5 squarings (LCHUNK = 32), per channel
    float Lr0 = lre0, Li0 = lim0, Lr1 = lre1, Li1 = lim1;
#pragma unroll
    for (int s = 0; s < 5; s++) {
        float a0 = Lr0 * Lr0 - Li0 * Li0, q0 = 2.f * Lr0 * Li0; Lr0 = a0; Li0 = q0;
        float a1 = Lr1 * Lr1 - Li1 * Li1, q1 = 2.f * Lr1 * Li1; Lr1 = a1; Li1 = q1;
    }
    // Horner prefix: p = h0; for j<c: p = L*p + carry[j]  (== old scan2's chain)
    float fr0 = h0[b * 512 + 2 * n2], fi0 = 0.f;
    float fr1 = h0[b * 512 + 2 * n2 + 1], fi1 = 0.f;
    size_t cb = (size_t)b * NCHUNK * 512 + 2 * n2;
#pragma unroll 4
    for (int j = 0; j < c; j++) {
        float2 ar = *(const float2*)(cRe + cb + (size_t)j * 512);
        float2 ai = *(const float2*)(cIm + cb + (size_t)j * 512);
        float nr0 = Lr0 * fr0 - Li0 * fi0 + ar.x;
        float ni0 = Lr0 * fi0 + Li0 * fr0 + ai.x;
        fr0 = nr0; fi0 = ni0;
        float nr1 = Lr1 * fr1 - Li1 * fi1 + ar.y;
        float ni1 = Lr1 * fi1 + Li1 * fr1 + ai.y;
        fr1 = nr1; fi1 = ni1;
    }
    if (c == NCHUNK - 1) {
        // newH = L*p[127] + carry[127]
        float2 ar = *(const float2*)(cRe + cb + (size_t)(NCHUNK - 1) * 512);
        float2 ai = *(const float2*)(cIm + cb + (size_t)(NCHUNK - 1) * 512);
        float cr0 = Lr0 * fr0 - Li0 * fi0 + ar.x;
        float ci0 = Lr0 * fi0 + Li0 * fr0 + ai.x;
        float cr1 = Lr1 * fr1 - Li1 * fi1 + ar.y;
        float ci1 = Lr1 * fi1 + Li1 * fr1 + ai.y;
        size_t i0 = (size_t)b * 512 + 2 * n2;
        if (newh_mode == 1) {
            newH[i0] = cr0; newH[i0 + 1] = cr1;
            newH[(size_t)NBATCH * 512 + i0] = ci0;
            newH[(size_t)NBATCH * 512 + i0 + 1] = ci1;
        } else if (newh_mode == 2) {
            newH[i0] = cr0; newH[i0 + 1] = cr1;
        } else {
            newH[i0 * 2] = cr0; newH[i0 * 2 + 1] = ci0;
            newH[(i0 + 1) * 2] = cr1; newH[(i0 + 1) * 2 + 1] = ci1;
        }
    }
    // phase 3: local re-scan + lambda^{j+1}*entering, write H bf16 [re|im] rows
    float pr0 = lre0, pi0 = lim0, pr1 = lre1, pi1 = lim1;
    float hr0 = 0.f, hi0 = 0.f, hr1 = 0.f, hi1 = 0.f;
    size_t row0 = (size_t)b * T_LEN + (size_t)c * LCHUNK;
#pragma unroll 4
    for (int j = 0; j < LCHUNK; j++) {
        size_t base = (row0 + j) * 512 + 2 * n2;
        ushort2 ur = *(const ushort2*)(BuRe + base);
        ushort2 ui = *(const ushort2*)(BuIm + base);
        float br0 = b2f(ur.x), br1 = b2f(ur.y), bi0 = b2f(ui.x), bi1 = b2f(ui.y);
        float nr0 = lre0 * hr0 - lim0 * hi0 + br0;
        float ni0 = lre0 * hi0 + lim0 * hr0 + bi0;
        hr0 = nr0; hi0 = ni0;
        float nr1 = lre1 * hr1 - lim1 * hi1 + br1;
        float ni1 = lre1 * hi1 + lim1 * hr1 + bi1;
        hr1 = nr1; hi1 = ni1;
        float vr0 = hr0 + pr0 * fr0 - pi0 * fi0;
        float vi0 = hi0 + pr0 * fi0 + pi0 * fr0;
        float vr1 = hr1 + pr1 * fr1 - pi1 * fi1;
        float vi1 = hi1 + pr1 * fi1 + pi1 * fr1;
        size_t hrow = (row0 + j) * 1024;
        ushort2 wre, wim;
        wre.x = f2b(vr0); wre.y = f2b(vr1);
        wim.x = f2b(vi0); wim.y = f2b(vi1);
        *(ushort2*)(Hbf + hrow + 2 * n2) = wre;
        *(ushort2*)(Hbf + hrow + 512 + 2 * n2) = wim;
        float npr0 = pr0 * lre0 - pi0 * lim0;
        float npi0 = pr0 * lim0 + pi0 * lre0;
        pr0 = npr0; pi0 = npi0;
        float npr1 = pr1 * lre1 - pi1 * lim1;
        float npi1 = pr1 * lim1 + pi1 * lre1;
        pr1 = npr1; pi1 = npi1;
    }
}

// ---------------- launch ----------------

extern "C" void kernel_launch(void* const* d_in, const int* in_sizes, int n_in,
                              void* d_out, int out_size, void* d_ws, size_t ws_size,
                              hipStream_t stream) {
    const float* x         = (const float*)d_in[0];
    const float* h0        = (const float*)d_in[1];
    const float* nu_log    = (const float*)d_in[2];
    const float* theta_log = (const float*)d_in[3];
    const float* B_re      = (const float*)d_in[4];
    const float* B_im      = (const float*)d_in[5];
    const float* C_re      = (const float*)d_in[6];
    const float* C_im      = (const float*)d_in[7];
    const float* D_param   = (const float*)d_in[8];
    const float* gamma_log = (const float*)d_in[9];

    char* ws = (char*)d_ws;
    size_t off = 0;
    ushort* Xb   = (ushort*)(ws + off); off += (size_t)MROWS * 512 * 2;
    ushort* BT   = (ushort*)(ws + off); off += (size_t)1024 * 512 * 2;
    ushort* CT   = (ushort*)(ws + off); off += (size_t)512 * 1024 * 2;
    ushort* BuRe = (ushort*)(ws + off); off += (size_t)MROWS * 512 * 2;
    ushort* BuIm = (ushort*)(ws + off); off += (size_t)MROWS * 512 * 2;
    ushort* Hbf  = (ushort*)(ws + off); off += (size_t)MROWS * 1024 * 2;
    float*  cRe  = (float*)(ws + off); off += (size_t)NBATCH * NCHUNK * 512 * 4;
    float*  cIm  = (float*)(ws + off); off += (size_t)NBATCH * NCHUNK * 512 * 4;

    float* y_out = (float*)d_out;
    float* newH  = (float*)d_out + (size_t)MROWS * 512;

    const int tail = out_size - MROWS * 512;
    int newh_mode = 0;
    if (tail == NBATCH * 512 * 2) newh_mode = 1;       // planar [re|im] (validated)
    else if (tail == NBATCH * 512) newh_mode = 2;

    // prep: x->bf16 + coalesced B/C transposes
    k_prep<<<dim3(XBLK + TBLK), dim3(256), 0, stream>>>(
        x, B_re, B_im, gamma_log, C_re, C_im, Xb, BT, CT);

    // GEMM1: Bu(bf16 planes) = Xb (32768x512) * BT^T (512x1024); 2048 blocks
    k_gemm<512, 1, 8><<<dim3(2048), dim3(256), 0, stream>>>(
        Xb, BT, BuRe, BuIm, nullptr, nullptr, nullptr);

    // scan: local carries, then fused prefix+phase3
    k_scan1<<<dim3(NBATCH * NCHUNK), dim3(256), 0, stream>>>(BuRe, BuIm, nu_log, theta_log, cRe, cIm);
    k_scanB<<<dim3(NBATCH * NCHUNK), dim3(256), 0, stream>>>(
        BuRe, BuIm, cRe, cIm, h0, nu_log, theta_log, Hbf, newH, newh_mode);

    // GEMM2: y = Hbf (32768x1024) * CT^T (1024x512) + D*x; 1024 blocks
    k_gemm<1024, 2, 4><<<dim3(1024), dim3(256), 0, stream>>>(
        Hbf, CT, nullptr, nullptr, y_out, x, D_param);
}